// Round 4
// baseline (616.241 us; speedup 1.0000x reference)
//
#include <hip/hip_runtime.h>

// Fused NeRF-MLP. Round 4: explicit A/B register double-buffering per K-step,
// non-temporal streaming loads (protect weight residency in L2), in-register
// sigma/rgb heads (VALU dot + shfl reduce; no LDS round-trip for d2/d4).
// 4096 blocks x 256 thr (4 waves), 64 rows/block, wave = 64ch x 64rows.

typedef __bf16 bf16x8 __attribute__((ext_vector_type(8)));
typedef float  f32x4  __attribute__((ext_vector_type(4)));
typedef float  f32x4v __attribute__((ext_vector_type(4)));
typedef short  short8 __attribute__((ext_vector_type(8)));

#define NROWS (8192 * 32)
#define MT 64
#define RS 264  // LDS act row stride (528 B: 4-bank row step -> ~2-way max, free)
#define SCR_OFF (2 * MT * RS)                 // scratch offset in ushort units
#define SMEM_BYTES (2 * MT * RS * 2 + 3072)   // 70656 B -> 2 blocks/CU

// packed-weight section offsets (bf16 elems) in d_ws
#define P0B   0        // W0^T   K=64(pad 63),  OUT=256 : 16384
#define P1B   16384    // W1     K=256, OUT=256          : 65536
#define P2B   81920    // W2     K=512, OUT=256          : 131072
#define PSB   212992   // (unused since r4)              : 4096
#define P3B   217088   // W3     K=512, OUT=256          : 131072
#define P4AB  348160   // W4[:256]      K=256, OUT=256   : 65536
#define P4BB  413696   // W4[256:283]   K=32(pad 27)     : 8192
#define PRB   421888   // (unused since r4)              : 4096
#define PTOT  425984

__device__ __forceinline__ unsigned short f2bf(float f) {
  unsigned u = __builtin_bit_cast(unsigned, f);
  u += 0x7fffu + ((u >> 16) & 1u);   // RNE
  return (unsigned short)(u >> 16);
}
__device__ __forceinline__ unsigned cvt_pk(float lo, float hi) {
  unsigned r;
  asm("v_cvt_pk_bf16_f32 %0, %1, %2" : "=v"(r) : "v"(lo), "v"(hi));
  return r;
}
__device__ __forceinline__ bf16x8 cvt8(f32x4v x, f32x4v y) {
  unsigned u0 = cvt_pk(x[0], x[1]), u1 = cvt_pk(x[2], x[3]);
  unsigned u2 = cvt_pk(y[0], y[1]), u3 = cvt_pk(y[2], y[3]);
  short8 s;
  s[0] = (short)(u0 & 0xffff); s[1] = (short)(u0 >> 16);
  s[2] = (short)(u1 & 0xffff); s[3] = (short)(u1 >> 16);
  s[4] = (short)(u2 & 0xffff); s[5] = (short)(u2 >> 16);
  s[6] = (short)(u3 & 0xffff); s[7] = (short)(u3 >> 16);
  return __builtin_bit_cast(bf16x8, s);
}
__device__ __forceinline__ bf16x8 as_bf(short8 s) {
  return __builtin_bit_cast(bf16x8, s);
}

// ---------------- pre-pass: pack weights to bf16 fragment layout ------------
// pack[((kt*OUTP + o)*4 + seg)*8 + j] = W[kt*32 + seg*8 + j][o]
__global__ void prep_pack(const float* __restrict__ W0, const float* __restrict__ W1,
                          const float* __restrict__ W2, const float* __restrict__ Ws,
                          const float* __restrict__ W3, const float* __restrict__ W4,
                          const float* __restrict__ Wr, const float* __restrict__ app,
                          const float* __restrict__ b4,
                          unsigned short* __restrict__ pack, float* __restrict__ b4p,
                          float* __restrict__ wrT)
{
  int gid = blockIdx.x * 256 + threadIdx.x;
  if (gid < PTOT) {
    const float* W; int OUTP, OUTR, Kreal, base, krow = 0;
    if      (gid < P1B)  { W = W0; OUTP = 256; OUTR = 256; Kreal = 63;  base = P0B; }
    else if (gid < P2B)  { W = W1; OUTP = 256; OUTR = 256; Kreal = 256; base = P1B; }
    else if (gid < PSB)  { W = W2; OUTP = 256; OUTR = 256; Kreal = 512; base = P2B; }
    else if (gid < P3B)  { W = Ws; OUTP = 16;  OUTR = 1;   Kreal = 256; base = PSB; }
    else if (gid < P4AB) { W = W3; OUTP = 256; OUTR = 256; Kreal = 512; base = P3B; }
    else if (gid < P4BB) { W = W4; OUTP = 256; OUTR = 256; Kreal = 256; base = P4AB; }
    else if (gid < PRB)  { W = W4; OUTP = 256; OUTR = 256; Kreal = 27;  base = P4BB; krow = 256; }
    else                 { W = Wr; OUTP = 16;  OUTR = 3;   Kreal = 256; base = PRB; }
    int local = gid - base;
    int j   = local & 7;
    int seg = (local >> 3) & 3;
    int rest = local >> 5;
    int o  = rest & (OUTP - 1);
    int kt = rest >> ((OUTP == 256) ? 8 : 4);
    int k  = kt * 32 + seg * 8 + j;
    float v = 0.f;
    if (k < Kreal && o < OUTR) v = W[(long)(k + krow) * OUTR + o];
    pack[gid] = f2bf(v);
  } else if (gid < PTOT + 256) {
    int o = gid - PTOT;
    float a = b4[o];
    for (int i = 0; i < 48; ++i) a += app[i] * W4[(long)(283 + i) * 256 + o];
    b4p[o] = a;
  } else if (gid < PTOT + 256 + 768) {
    int idx = gid - (PTOT + 256);
    int c = idx >> 8, ch = idx & 255;
    wrT[c * 256 + ch] = Wr[ch * 3 + c];
  }
}

// ---------------- main fused kernel ----------------------------------------
__global__ __launch_bounds__(256, 2)
void nerf_fused(const float* __restrict__ pos, const float* __restrict__ dirs,
                const float* __restrict__ gemo, const float* __restrict__ color,
                const float* __restrict__ mask,
                const unsigned short* __restrict__ wp,
                const float* __restrict__ b0, const float* __restrict__ b1,
                const float* __restrict__ b2, const float* __restrict__ bsv,
                const float* __restrict__ b3, const float* __restrict__ b4p,
                const float* __restrict__ brv,
                const float* __restrict__ Wsf, const float* __restrict__ wrT,
                float* __restrict__ osig, float* __restrict__ orgb)
{
  extern __shared__ unsigned short smem[];
  unsigned short* buf0 = smem;            // [64][RS]
  unsigned short* buf1 = smem + MT * RS;  // [64][RS]
  float* scr = (float*)(smem + SCR_OFF);  // 3072 B head-reduce scratch

  const int tid  = (int)threadIdx.x;
  const int w    = tid >> 6;
  const int lane = tid & 63;
  const int l16  = lane & 15;
  const int seg  = lane >> 4;
  const int chb  = w * 64;              // 4 disjoint 64-ch slices
  const long R0  = (long)blockIdx.x * MT;
  const int rot  = (int)(blockIdx.x & 7);

  f32x4 acc[4][4];

  auto ldA = [&](int baseElems, int o, int kt) -> bf16x8 {
    const bf16x8* p = (const bf16x8*)(wp + baseElems);
    return p[(kt * 256 + o) * 4 + seg];
  };
  auto ldB_lds = [&](const unsigned short* buf, int rt, int kt) -> bf16x8 {
    int row = rt * 16 + l16;
    return *(const bf16x8*)(buf + row * RS + kt * 32 + seg * 8);
  };
  auto ldB_gen = [&](const float* __restrict__ p, int stride, int Kreal,
                     int rt, int ktl) -> bf16x8 {
    long row = R0 + rt * 16 + l16;
    const float* q = p + row * stride;
    int k0 = ktl * 32 + seg * 8;
    short8 s;
#pragma unroll
    for (int j = 0; j < 8; ++j) {
      float v = (k0 + j < Kreal) ? __builtin_nontemporal_load(q + k0 + j) : 0.0f;
      s[j] = (short)f2bf(v);
    }
    return as_bf(s);
  };
  auto initAcc = [&](const float* __restrict__ b) {
#pragma unroll
    for (int ct = 0; ct < 4; ++ct) {
      float4 bv = *(const float4*)(b + chb + ct * 16 + seg * 4);
      f32x4 t; t[0] = bv.x; t[1] = bv.y; t[2] = bv.z; t[3] = bv.w;
#pragma unroll
      for (int rt = 0; rt < 4; ++rt) acc[ct][rt] = t;
    }
  };
  auto storeAct = [&](unsigned short* __restrict__ buf) {
#pragma unroll
    for (int ct = 0; ct < 4; ++ct)
#pragma unroll
      for (int rt = 0; rt < 4; ++rt) {
        int row = rt * 16 + l16;
        int ch  = chb + ct * 16 + seg * 4;
        f32x4 v = acc[ct][rt];
        uint2 u;
        u.x = cvt_pk(fmaxf(v[0], 0.f), fmaxf(v[1], 0.f));
        u.y = cvt_pk(fmaxf(v[2], 0.f), fmaxf(v[3], 0.f));
        *(uint2*)(buf + row * RS + ch) = u;  // ds_write_b64
      }
  };

// simple step (small layers): 4 B-frags + 4 A-loads -> 16 MFMA
#define GSTEP(ABASE, kt, BLOADER)                                              \
  {                                                                            \
    bf16x8 Bf[4];                                                              \
    _Pragma("unroll") for (int rt = 0; rt < 4; ++rt) Bf[rt] = BLOADER;         \
    _Pragma("unroll") for (int ct = 0; ct < 4; ++ct) {                         \
      bf16x8 Af = ldA(ABASE, chb + ct * 16 + l16, kt);                         \
      _Pragma("unroll") for (int rt = 0; rt < 4; ++rt)                         \
        acc[ct][rt] = __builtin_amdgcn_mfma_f32_16x16x32_bf16(                 \
            Af, Bf[rt], acc[ct][rt], 0, 0, 0);                                 \
    }                                                                          \
  }

// 8-step half, B from LDS, A from L2: distance-1 double-buffered A and B
#define LHALF_P(ABASE, BUF)                                                    \
  {                                                                            \
    bf16x8 Al[2][4], Bl[2][4];                                                 \
    {                                                                          \
      int kt0 = rot & 7;                                                       \
      _Pragma("unroll") for (int rt = 0; rt < 4; ++rt)                         \
        Bl[0][rt] = ldB_lds(BUF, rt, kt0);                                     \
      _Pragma("unroll") for (int ct = 0; ct < 4; ++ct)                         \
        Al[0][ct] = ldA(ABASE, chb + ct * 16 + l16, kt0);                      \
    }                                                                          \
    _Pragma("unroll") for (int i = 0; i < 8; ++i) {                            \
      if (i + 1 < 8) {                                                         \
        int ktn = (i + 1 + rot) & 7;                                           \
        _Pragma("unroll") for (int rt = 0; rt < 4; ++rt)                       \
          Bl[(i + 1) & 1][rt] = ldB_lds(BUF, rt, ktn);                         \
        _Pragma("unroll") for (int ct = 0; ct < 4; ++ct)                       \
          Al[(i + 1) & 1][ct] = ldA(ABASE, chb + ct * 16 + l16, ktn);          \
      }                                                                        \
      _Pragma("unroll") for (int ct = 0; ct < 4; ++ct)                         \
        _Pragma("unroll") for (int rt = 0; rt < 4; ++rt)                       \
          acc[ct][rt] = __builtin_amdgcn_mfma_f32_16x16x32_bf16(               \
              Al[i & 1][ct], Bl[i & 1][rt], acc[ct][rt], 0, 0, 0);             \
    }                                                                          \
  }

// 8-step half, B streamed NT from global f32 [N,256] (distance-2),
// A from L2 (distance-1)
#define GHALF_P(ABASE, P)                                                      \
  {                                                                            \
    f32x4v pre[2][4][2];                                                       \
    bf16x8 Ag[2][4];                                                           \
    _Pragma("unroll") for (int s = 0; s < 2; ++s) {                            \
      int ktl = (s + rot) & 7;                                                 \
      _Pragma("unroll") for (int rt = 0; rt < 4; ++rt) {                       \
        const f32x4v* q = (const f32x4v*)((P) + (R0 + rt * 16 + l16) * 256 +   \
                                          ktl * 32 + seg * 8);                 \
        pre[s][rt][0] = __builtin_nontemporal_load(q);                         \
        pre[s][rt][1] = __builtin_nontemporal_load(q + 1);                     \
      }                                                                        \
    }                                                                          \
    {                                                                          \
      int kt0 = 8 + (rot & 7);                                                 \
      _Pragma("unroll") for (int ct = 0; ct < 4; ++ct)                         \
        Ag[0][ct] = ldA(ABASE, chb + ct * 16 + l16, kt0);                      \
    }                                                                          \
    _Pragma("unroll") for (int i = 0; i < 8; ++i) {                            \
      bf16x8 Bf[4];                                                            \
      _Pragma("unroll") for (int rt = 0; rt < 4; ++rt)                         \
        Bf[rt] = cvt8(pre[i & 1][rt][0], pre[i & 1][rt][1]);                   \
      if (i + 2 < 8) {                                                         \
        int ktl = (i + 2 + rot) & 7;                                           \
        _Pragma("unroll") for (int rt = 0; rt < 4; ++rt) {                     \
          const f32x4v* q = (const f32x4v*)((P) + (R0 + rt * 16 + l16) * 256 + \
                                            ktl * 32 + seg * 8);               \
          pre[i & 1][rt][0] = __builtin_nontemporal_load(q);                   \
          pre[i & 1][rt][1] = __builtin_nontemporal_load(q + 1);               \
        }                                                                      \
      }                                                                        \
      if (i + 1 < 8) {                                                         \
        int ktn = 8 + ((i + 1 + rot) & 7);                                     \
        _Pragma("unroll") for (int ct = 0; ct < 4; ++ct)                       \
          Ag[(i + 1) & 1][ct] = ldA(ABASE, chb + ct * 16 + l16, ktn);          \
      }                                                                        \
      _Pragma("unroll") for (int ct = 0; ct < 4; ++ct)                         \
        _Pragma("unroll") for (int rt = 0; rt < 4; ++rt)                       \
          acc[ct][rt] = __builtin_amdgcn_mfma_f32_16x16x32_bf16(               \
              Ag[i & 1][ct], Bf[rt], acc[ct][rt], 0, 0, 0);                    \
    }                                                                          \
  }

  // ---- L0: d0 = relu(pos @ W0 + b0) -> buf0
  initAcc(b0);
  GSTEP(P0B, 0, ldB_gen(pos, 63, 63, rt, 0));
  GSTEP(P0B, 1, ldB_gen(pos, 63, 63, rt, 1));
  storeAct(buf0);
  __syncthreads();

  // ---- L1: d1 = relu(d0 @ W1 + b1) -> buf1
  initAcc(b1);
  LHALF_P(P1B, buf0);
  storeAct(buf1);
  __syncthreads();

  // ---- L2: d2 = [d1|gemo] @ W2 + b2 (pre-relu in acc; never stored)
  initAcc(b2);
  GHALF_P(P2B, gemo);
  LHALF_P(P2B, buf1);

  // ---- sigma head (in-register): softplus(relu(d2) @ Ws + bs) * mask
  {
    float p[4];
#pragma unroll
    for (int rt = 0; rt < 4; ++rt) {
      float s = 0.f;
#pragma unroll
      for (int ct = 0; ct < 4; ++ct) {
        float4 w4 = *(const float4*)(Wsf + chb + ct * 16 + seg * 4);
        f32x4 a = acc[ct][rt];
        s += fmaxf(a[0], 0.f) * w4.x + fmaxf(a[1], 0.f) * w4.y +
             fmaxf(a[2], 0.f) * w4.z + fmaxf(a[3], 0.f) * w4.w;
      }
      s += __shfl_xor(s, 16);
      s += __shfl_xor(s, 32);
      p[rt] = s;
    }
    if (seg == 0) {
#pragma unroll
      for (int rt = 0; rt < 4; ++rt) scr[w * 64 + rt * 16 + l16] = p[rt];
    }
  }
  __syncthreads();
  if (tid < 64) {
    float s = scr[tid] + scr[64 + tid] + scr[128 + tid] + scr[192 + tid] + bsv[0];
    float sp = fmaxf(s, 0.f) + log1pf(expf(-fabsf(s)));
    float m = __builtin_nontemporal_load(mask + R0 + tid);
    __builtin_nontemporal_store(sp * m, osig + R0 + tid);
  }

  // ---- L3: d3 = relu([d1|color] @ W3 + b3) -> buf0
  initAcc(b3);
  GHALF_P(P3B, color);
  LHALF_P(P3B, buf1);
  storeAct(buf0);
  __syncthreads();

  // ---- L4: d4 = [d3|dir|app] @ W4 + b4' (pre-relu in acc; never stored)
  initAcc(b4p);
  GSTEP(P4BB, 0, ldB_gen(dirs, 27, 27, rt, 0));
  LHALF_P(P4AB, buf0);

  // ---- rgb head (in-register): sigmoid(relu(d4) @ Wr + br)
  {
#pragma unroll
    for (int ct = 0; ct < 4; ++ct)
#pragma unroll
      for (int rt = 0; rt < 4; ++rt) {
        f32x4 a = acc[ct][rt];
        a[0] = fmaxf(a[0], 0.f); a[1] = fmaxf(a[1], 0.f);
        a[2] = fmaxf(a[2], 0.f); a[3] = fmaxf(a[3], 0.f);
        acc[ct][rt] = a;
      }
#pragma unroll
    for (int c = 0; c < 3; ++c) {
      float p[4];
#pragma unroll
      for (int rt = 0; rt < 4; ++rt) {
        float s = 0.f;
#pragma unroll
        for (int ct = 0; ct < 4; ++ct) {
          float4 w4 = *(const float4*)(wrT + c * 256 + chb + ct * 16 + seg * 4);
          f32x4 a = acc[ct][rt];
          s += a[0] * w4.x + a[1] * w4.y + a[2] * w4.z + a[3] * w4.w;
        }
        s += __shfl_xor(s, 16);
        s += __shfl_xor(s, 32);
        p[rt] = s;
      }
      if (seg == 0) {
#pragma unroll
        for (int rt = 0; rt < 4; ++rt)
          scr[c * 256 + w * 64 + rt * 16 + l16] = p[rt];
      }
    }
  }
  __syncthreads();
  if (tid < 64) {
#pragma unroll
    for (int c = 0; c < 3; ++c) {
      float s = scr[c * 256 + tid] + scr[c * 256 + 64 + tid] +
                scr[c * 256 + 128 + tid] + scr[c * 256 + 192 + tid] + brv[c];
      float r = 1.f / (1.f + expf(-s));
      __builtin_nontemporal_store(r, orgb + (R0 + tid) * 3 + c);
    }
  }
#undef GSTEP
#undef LHALF_P
#undef GHALF_P
}

extern "C" void kernel_launch(void* const* d_in, const int* in_sizes, int n_in,
                              void* d_out, int out_size, void* d_ws, size_t ws_size,
                              hipStream_t stream) {
  const float* pos   = (const float*)d_in[0];
  const float* dirs  = (const float*)d_in[1];
  const float* app   = (const float*)d_in[2];
  const float* gemo  = (const float*)d_in[3];
  const float* color = (const float*)d_in[4];
  const float* mask  = (const float*)d_in[5];
  // d_in[6] = num_inters (fixed 32, shapes are static)
  const float* W0 = (const float*)d_in[7];   const float* b0 = (const float*)d_in[8];
  const float* W1 = (const float*)d_in[9];   const float* b1 = (const float*)d_in[10];
  const float* W2 = (const float*)d_in[11];  const float* b2 = (const float*)d_in[12];
  const float* Ws = (const float*)d_in[13];  const float* bs = (const float*)d_in[14];
  const float* W3 = (const float*)d_in[15];  const float* b3 = (const float*)d_in[16];
  const float* W4 = (const float*)d_in[17];  const float* b4 = (const float*)d_in[18];
  const float* Wr = (const float*)d_in[19];  const float* br = (const float*)d_in[20];

  unsigned short* pack = (unsigned short*)d_ws;
  float* b4p = (float*)((char*)d_ws + (size_t)PTOT * 2);
  float* wrT = b4p + 256;

  float* osig = (float*)d_out;
  float* orgb = osig + NROWS;

  prep_pack<<<dim3((PTOT + 256 + 768 + 255) / 256), dim3(256), 0, stream>>>(
      W0, W1, W2, Ws, W3, W4, Wr, app, b4, pack, b4p, wrT);

  hipFuncSetAttribute((const void*)nerf_fused,
                      hipFuncAttributeMaxDynamicSharedMemorySize, SMEM_BYTES);

  nerf_fused<<<dim3(NROWS / MT), dim3(256), SMEM_BYTES, stream>>>(
      pos, dirs, gemo, color, mask, pack,
      b0, b1, b2, bs, b3, b4p, br, Ws, wrT, osig, orgb);
}